// Round 14
// baseline (30.745 us; speedup 1.0000x reference)
//
#include <hip/hip_runtime.h>
#include <cstdint>
#include <cstddef>

typedef _Float16 half8 __attribute__((ext_vector_type(8)));
typedef float f32x4 __attribute__((ext_vector_type(4)));

static constexpr int kN  = 256;          // state dim (N == K)
static constexpr int kBM = 64;           // rows per block (4 waves x 16)

// out[m][n] = sum_k c[m][k] * A_t[n][k] + b[n] * f[m]
// SINGLE dispatch. 256-thr blocks (4 waves), 64 KiB static LDS -> 2 blocks/CU.
// Each block packs ONE ks-half of A_t (fp32, L2/L3-resident) into f16 frag
// layout in LDS, computes on it, then overwrites LDS with the other half.
// Parity (bid&1) staggers which half a block starts with so co-resident
// blocks pull different halves. Structure identical to R10 otherwise.
__global__ __launch_bounds__(256, 2) void hippo_fused(
    const float* __restrict__ c, const float* __restrict__ f,
    const float* __restrict__ A_stacked, const float* __restrict__ Bst,
    const int* __restrict__ tptr, float* __restrict__ out)
{
    __shared__ _Float16 As[32768];   // 64 KiB: one ks-half of packed A

    const int tid  = threadIdx.x;
    const int l    = tid & 63;
    const int wid  = tid >> 6;          // 0..3
    const int lo16 = l & 15;
    const int hi4  = l >> 4;
    const int bid  = blockIdx.x;
    const int m0   = bid * kBM + wid * 16;
    const int hA   = bid & 1;           // first ks-half (parity-staggered)
    const int hB   = hA ^ 1;
    const int t    = tptr[0];

    const float* __restrict__ Abase = A_stacked + (size_t)t * kN * kN;

    // ---- 1) pack half hA into LDS: unit u=(nt,ks2), wave handles u=i*4+wid ----
    // LDS layout: frag u at bytes u*1024 + l*16  (read as Bs[u*64 + l])
    #pragma unroll
    for (int i = 0; i < 16; ++i) {
        const int u   = i * 4 + wid;    // 0..63
        const int nt  = u >> 2;
        const int ks2 = u & 3;
        const float* p = Abase + (size_t)(nt * 16 + lo16) * kN
                         + (hA * 4 + ks2) * 32 + (hi4 << 3);
        f32x4 v0 = *(const f32x4*)p;
        f32x4 v1 = *(const f32x4*)(p + 4);
        half8 h;
        h[0] = (_Float16)v0[0]; h[1] = (_Float16)v0[1];
        h[2] = (_Float16)v0[2]; h[3] = (_Float16)v0[3];
        h[4] = (_Float16)v1[0]; h[5] = (_Float16)v1[1];
        h[6] = (_Float16)v1[2]; h[7] = (_Float16)v1[3];
        *(half8*)(As + (size_t)u * 512 + (size_t)l * 8) = h;
    }

    // ---- 2) c loads for half hA ----
    const float* __restrict__ cptr = c + (size_t)(m0 + lo16) * kN + (hi4 << 3);
    f32x4 cv0[4], cv1[4];
    #pragma unroll
    for (int ks = 0; ks < 4; ++ks) {
        cv0[ks] = *(const f32x4*)(cptr + hA * 128 + ks * 32);
        cv1[ks] = *(const f32x4*)(cptr + hA * 128 + ks * 32 + 4);
    }

    // ---- 3) bias loads ----
    const float* __restrict__ brow = Bst + (size_t)t * kN;
    float bvs[16];
    #pragma unroll
    for (int nt = 0; nt < 16; ++nt) bvs[nt] = brow[nt * 16 + lo16];
    float fv[4];
    #pragma unroll
    for (int r = 0; r < 4; ++r) fv[r] = f[m0 + (hi4 << 2) + r];

    __syncthreads();   // pack(hA) visible; c(hA) drained

    // ---- 4) cvt af (cv dies); issue c loads for half hB early ----
    half8 af[4];
    #pragma unroll
    for (int ks = 0; ks < 4; ++ks) {
        af[ks][0] = (_Float16)cv0[ks][0]; af[ks][1] = (_Float16)cv0[ks][1];
        af[ks][2] = (_Float16)cv0[ks][2]; af[ks][3] = (_Float16)cv0[ks][3];
        af[ks][4] = (_Float16)cv1[ks][0]; af[ks][5] = (_Float16)cv1[ks][1];
        af[ks][6] = (_Float16)cv1[ks][2]; af[ks][7] = (_Float16)cv1[ks][3];
    }
    f32x4 dv0[4], dv1[4];
    #pragma unroll
    for (int ks = 0; ks < 4; ++ks) {
        dv0[ks] = *(const f32x4*)(cptr + hB * 128 + ks * 32);
        dv1[ks] = *(const f32x4*)(cptr + hB * 128 + ks * 32 + 4);
    }

    // ---- 5) compute half hA (ks-outer, 16 chains) ----
    const half8* __restrict__ Bs = (const half8*)As;
    f32x4 acc[16];
    #pragma unroll
    for (int i = 0; i < 16; ++i) acc[i] = (f32x4){0.f, 0.f, 0.f, 0.f};
    #pragma unroll
    for (int ks = 0; ks < 4; ++ks) {
        #pragma unroll
        for (int nt = 0; nt < 16; ++nt) {
            half8 bf = Bs[(nt * 4 + ks) * 64 + l];
            acc[nt] = __builtin_amdgcn_mfma_f32_16x16x32_f16(af[ks], bf, acc[nt], 0, 0, 0);
        }
    }

    __syncthreads();   // all reads of half hA done -> safe to overwrite

    // ---- 6) pack half hB into LDS ----
    #pragma unroll
    for (int i = 0; i < 16; ++i) {
        const int u   = i * 4 + wid;
        const int nt  = u >> 2;
        const int ks2 = u & 3;
        const float* p = Abase + (size_t)(nt * 16 + lo16) * kN
                         + (hB * 4 + ks2) * 32 + (hi4 << 3);
        f32x4 v0 = *(const f32x4*)p;
        f32x4 v1 = *(const f32x4*)(p + 4);
        half8 h;
        h[0] = (_Float16)v0[0]; h[1] = (_Float16)v0[1];
        h[2] = (_Float16)v0[2]; h[3] = (_Float16)v0[3];
        h[4] = (_Float16)v1[0]; h[5] = (_Float16)v1[1];
        h[6] = (_Float16)v1[2]; h[7] = (_Float16)v1[3];
        *(half8*)(As + (size_t)u * 512 + (size_t)l * 8) = h;
    }

    __syncthreads();   // pack(hB) visible

    // ---- 7) cvt ag (dv dies) + compute half hB ----
    half8 ag[4];
    #pragma unroll
    for (int ks = 0; ks < 4; ++ks) {
        ag[ks][0] = (_Float16)dv0[ks][0]; ag[ks][1] = (_Float16)dv0[ks][1];
        ag[ks][2] = (_Float16)dv0[ks][2]; ag[ks][3] = (_Float16)dv0[ks][3];
        ag[ks][4] = (_Float16)dv1[ks][0]; ag[ks][5] = (_Float16)dv1[ks][1];
        ag[ks][6] = (_Float16)dv1[ks][2]; ag[ks][7] = (_Float16)dv1[ks][3];
    }
    #pragma unroll
    for (int ks = 0; ks < 4; ++ks) {
        #pragma unroll
        for (int nt = 0; nt < 16; ++nt) {
            half8 bf = Bs[(nt * 4 + ks) * 64 + l];
            acc[nt] = __builtin_amdgcn_mfma_f32_16x16x32_f16(ag[ks], bf, acc[nt], 0, 0, 0);
        }
    }

    // ---- 8) epilogue ----
    float* __restrict__ obase = out + (size_t)(m0 + (hi4 << 2)) * kN + lo16;
    #pragma unroll
    for (int nt = 0; nt < 16; ++nt) {
        #pragma unroll
        for (int r = 0; r < 4; ++r)
            obase[(size_t)r * kN + nt * 16] = acc[nt][r] + bvs[nt] * fv[r];
    }
}

extern "C" void kernel_launch(void* const* d_in, const int* in_sizes, int n_in,
                              void* d_out, int out_size, void* d_ws, size_t ws_size,
                              hipStream_t stream) {
    const float* c   = (const float*)d_in[0];
    const float* f   = (const float*)d_in[1];
    const float* A   = (const float*)d_in[2];
    const float* B   = (const float*)d_in[3];
    const int*   t   = (const int*)d_in[4];
    float* out = (float*)d_out;

    const int batch = in_sizes[0] / kN;   // 32768

    hipLaunchKernelGGL(hippo_fused, dim3(batch / kBM), dim3(256), 0, stream,
                       c, f, A, B, t, out);
}

// Round 15
// 22.679 us; speedup vs baseline: 1.3557x; 1.3557x over previous
//
#include <hip/hip_runtime.h>
#include <cstdint>
#include <cstddef>

typedef _Float16 half8 __attribute__((ext_vector_type(8)));
typedef float f32x4 __attribute__((ext_vector_type(4)));

static constexpr int kN  = 256;            // state dim (N == K)
static constexpr int kBM = 64;             // rows per block (4 waves x 16)
static constexpr size_t kHalfB  = 64 * 1024;   // one ks-half of packed B
static constexpr size_t kLDS    = kHalfB;      // 64 KiB -> 2 blocks/CU

// Pack A_stacked[t] (fp32 [n][k]) into f16 frag order, ks-half outermost:
// a16[ ((ksh*16 + nt)*4 + ks2)*64 + l ] (half8 units)
//   = A[nt*16 + (l&15)][ (ksh*4 + ks2)*32 + (l>>4)*8 + j ]
__global__ __launch_bounds__(256) void hippo_prep(
    const float* __restrict__ A_stacked, const int* __restrict__ tptr,
    _Float16* __restrict__ a16)
{
    const int t = tptr[0];
    const float* __restrict__ A = A_stacked + (size_t)t * kN * kN;
    const int tid = blockIdx.x * 256 + threadIdx.x;   // 0..8191
    const int ksh = tid >> 12;
    const int nt  = (tid >> 8) & 15;
    const int ks2 = (tid >> 6) & 3;
    const int l   = tid & 63;
    const int row = nt * 16 + (l & 15);
    const int k0  = (ksh * 4 + ks2) * 32 + ((l >> 4) << 3);
    const float* __restrict__ src = A + (size_t)row * kN + k0;
    f32x4 v0 = *(const f32x4*)(src);
    f32x4 v1 = *(const f32x4*)(src + 4);
    half8 h;
    h[0] = (_Float16)v0[0]; h[1] = (_Float16)v0[1];
    h[2] = (_Float16)v0[2]; h[3] = (_Float16)v0[3];
    h[4] = (_Float16)v1[0]; h[5] = (_Float16)v1[1];
    h[6] = (_Float16)v1[2]; h[7] = (_Float16)v1[3];
    ((half8*)a16)[tid] = h;
}

// out[m][n] = sum_k c[m][k] * A_t[n][k] + b[n] * f[m]
// R10 structure (4-wave blocks, 64 KiB LDS ks-half staging, 2 blocks/CU,
// parity-staggered halves) + three overlap fixes:
//   - c(hB) issued BEFORE compute(hA)  (latency hides under MFMA)
//   - cvt ag placed between DMA(hB) issue and its drain barrier
//   - stores streamed per-nt through compute(hB)
__global__ __launch_bounds__(256, 2) void hippo_gemm(
    const float* __restrict__ c, const float* __restrict__ f,
    const float* __restrict__ Bst, const int* __restrict__ tptr,
    const _Float16* __restrict__ a16, float* __restrict__ out)
{
    extern __shared__ char lds_raw[];

    const int tid  = threadIdx.x;
    const int l    = tid & 63;
    const int wid  = tid >> 6;          // 0..3
    const int lo16 = l & 15;
    const int hi4  = l >> 4;
    const int bid  = blockIdx.x;
    const int m0   = bid * kBM + wid * 16;
    const int hA   = bid & 1;           // first ks-half (parity-staggered)
    const int hB   = hA ^ 1;

    // ---- DMA half hA into LDS (64 chunks of 1 KiB across 4 waves) ----
    const char* __restrict__ gsrcA = (const char*)a16 + (size_t)hA * kHalfB;
    #pragma unroll
    for (int i = 0; i < 16; ++i) {
        const size_t off = (size_t)(i * 4 + wid) * 1024 + (size_t)l * 16;
        __builtin_amdgcn_global_load_lds(
            (const __attribute__((address_space(1))) void*)(gsrcA + off),
            (__attribute__((address_space(3))) void*)(lds_raw + off),
            16, 0, 0);
    }

    // ---- c loads for half hA ----
    const float* __restrict__ cptr = c + (size_t)(m0 + lo16) * kN + (hi4 << 3);
    f32x4 cv0[4], cv1[4];
    #pragma unroll
    for (int ks = 0; ks < 4; ++ks) {
        cv0[ks] = *(const f32x4*)(cptr + hA * 128 + ks * 32);
        cv1[ks] = *(const f32x4*)(cptr + hA * 128 + ks * 32 + 4);
    }

    // ---- bias loads ----
    const int t = tptr[0];
    const float* __restrict__ brow = Bst + (size_t)t * kN;
    float bvs[16];
    #pragma unroll
    for (int nt = 0; nt < 16; ++nt) bvs[nt] = brow[nt * 16 + lo16];
    float fv[4];
    #pragma unroll
    for (int r = 0; r < 4; ++r) fv[r] = f[m0 + (hi4 << 2) + r];

    __syncthreads();   // drains DMA(hA) + c(hA)

    // ---- cvt af (cv dies) ----
    half8 af[4];
    #pragma unroll
    for (int ks = 0; ks < 4; ++ks) {
        af[ks][0] = (_Float16)cv0[ks][0]; af[ks][1] = (_Float16)cv0[ks][1];
        af[ks][2] = (_Float16)cv0[ks][2]; af[ks][3] = (_Float16)cv0[ks][3];
        af[ks][4] = (_Float16)cv1[ks][0]; af[ks][5] = (_Float16)cv1[ks][1];
        af[ks][6] = (_Float16)cv1[ks][2]; af[ks][7] = (_Float16)cv1[ks][3];
    }

    // ---- HOISTED: issue c loads for half hB (hide under compute hA) ----
    f32x4 dv0[4], dv1[4];
    #pragma unroll
    for (int ks = 0; ks < 4; ++ks) {
        dv0[ks] = *(const f32x4*)(cptr + hB * 128 + ks * 32);
        dv1[ks] = *(const f32x4*)(cptr + hB * 128 + ks * 32 + 4);
    }

    // ---- compute half hA (ks-outer, 16 chains) ----
    const half8* __restrict__ Bs = (const half8*)lds_raw;
    f32x4 acc[16];
    #pragma unroll
    for (int i = 0; i < 16; ++i) acc[i] = (f32x4){0.f, 0.f, 0.f, 0.f};
    #pragma unroll
    for (int ks = 0; ks < 4; ++ks) {
        #pragma unroll
        for (int nt = 0; nt < 16; ++nt) {
            half8 bf = Bs[(nt * 4 + ks) * 64 + l];
            acc[nt] = __builtin_amdgcn_mfma_f32_16x16x32_f16(af[ks], bf, acc[nt], 0, 0, 0);
        }
    }

    __syncthreads();   // all LDS reads of half hA complete -> safe to overwrite

    // ---- DMA half hB; cvt ag under its latency (dv already landed) ----
    const char* __restrict__ gsrcB = (const char*)a16 + (size_t)hB * kHalfB;
    #pragma unroll
    for (int i = 0; i < 16; ++i) {
        const size_t off = (size_t)(i * 4 + wid) * 1024 + (size_t)l * 16;
        __builtin_amdgcn_global_load_lds(
            (const __attribute__((address_space(1))) void*)(gsrcB + off),
            (__attribute__((address_space(3))) void*)(lds_raw + off),
            16, 0, 0);
    }
    half8 ag[4];
    #pragma unroll
    for (int ks = 0; ks < 4; ++ks) {
        ag[ks][0] = (_Float16)dv0[ks][0]; ag[ks][1] = (_Float16)dv0[ks][1];
        ag[ks][2] = (_Float16)dv0[ks][2]; ag[ks][3] = (_Float16)dv0[ks][3];
        ag[ks][4] = (_Float16)dv1[ks][0]; ag[ks][5] = (_Float16)dv1[ks][1];
        ag[ks][6] = (_Float16)dv1[ks][2]; ag[ks][7] = (_Float16)dv1[ks][3];
    }

    __syncthreads();   // drains DMA(hB)

    // ---- compute half hB, nt-outer, store each n-tile immediately ----
    float* __restrict__ obase = out + (size_t)(m0 + (hi4 << 2)) * kN + lo16;
    #pragma unroll
    for (int nt = 0; nt < 16; ++nt) {
        f32x4 a = acc[nt];
        #pragma unroll
        for (int ks = 0; ks < 4; ++ks) {
            half8 bf = Bs[(nt * 4 + ks) * 64 + l];
            a = __builtin_amdgcn_mfma_f32_16x16x32_f16(ag[ks], bf, a, 0, 0, 0);
        }
        #pragma unroll
        for (int r = 0; r < 4; ++r)
            obase[(size_t)r * kN + nt * 16] = a[r] + bvs[nt] * fv[r];
    }
}

extern "C" void kernel_launch(void* const* d_in, const int* in_sizes, int n_in,
                              void* d_out, int out_size, void* d_ws, size_t ws_size,
                              hipStream_t stream) {
    const float* c   = (const float*)d_in[0];
    const float* f   = (const float*)d_in[1];
    const float* A   = (const float*)d_in[2];
    const float* B   = (const float*)d_in[3];
    const int*   t   = (const int*)d_in[4];
    float* out = (float*)d_out;
    _Float16* a16 = (_Float16*)d_ws;   // 128 KiB packed A[t] f16, ks-half-major

    const int batch = in_sizes[0] / kN;   // 32768

    hipFuncSetAttribute((const void*)hippo_gemm,
                        hipFuncAttributeMaxDynamicSharedMemorySize,
                        (int)kLDS);

    hipLaunchKernelGGL(hippo_prep, dim3(32), dim3(256), 0, stream, A, t, a16);
    hipLaunchKernelGGL(hippo_gemm, dim3(batch / kBM), dim3(256), kLDS, stream,
                       c, f, B, t, a16, out);
}